// Round 1
// baseline (2101.175 us; speedup 1.0000x reference)
//
#include <hip/hip_runtime.h>
#include <cfloat>

// Problem constants (from reference): x (16,2048,256) fp32, weight (4096,256) fp32.
constexpr int E  = 256;    // quantizing_dim
constexpr int Qn = 4096;   // num_quantizing
constexpr int BM = 64;     // rows per block
constexpr int BN = 128;    // codewords per Q-tile
constexpr int BK = 64;     // K chunk staged in LDS
constexpr int PAD = 4;     // LDS row pad (stride 68 floats, keeps 16B alignment)
constexpr int TH = 256;    // threads per block

// One 64-lane wave per row: sum of squares of 256 floats.
__global__ __launch_bounds__(64) void row_sumsq_kernel(const float* __restrict__ src,
                                                       float* __restrict__ dst) {
    int row  = blockIdx.x;
    int lane = threadIdx.x;
    float4 v = ((const float4*)(src + (size_t)row * E))[lane];
    float s = v.x * v.x + v.y * v.y + v.z * v.z + v.w * v.w;
    #pragma unroll
    for (int off = 32; off > 0; off >>= 1) s += __shfl_down(s, off);
    if (lane == 0) dst[row] = s;
}

__global__ __launch_bounds__(TH) void vq_kernel(
    const float* __restrict__ x, const float* __restrict__ w,
    const float* __restrict__ x2, const float* __restrict__ w2,
    float* __restrict__ qdata, float* __restrict__ qidx)
{
    __shared__ float xs[BM][BK + PAD];
    __shared__ float ws[BN][BK + PAD];
    __shared__ float redS[BM][16];
    __shared__ int   redC[BM][16];
    __shared__ int   bestC[BM];

    const int tid = threadIdx.x;
    const int tr  = tid >> 4;   // 0..15
    const int tc  = tid & 15;   // 0..15
    const int r0  = blockIdx.x * BM;

    // rows owned: tr + 16*i (i<4); cols owned per tile: tc + 16*j (j<8)
    float best[4];
    int   bidx[4];
    #pragma unroll
    for (int i = 0; i < 4; ++i) { best[i] = FLT_MAX; bidx[i] = 0x7FFFFFFF; }

    float x2r[4];
    #pragma unroll
    for (int i = 0; i < 4; ++i) x2r[i] = x2[r0 + tr + 16 * i];

    for (int qt = 0; qt < Qn / BN; ++qt) {
        const int c0 = qt * BN;
        float acc[4][8];
        #pragma unroll
        for (int i = 0; i < 4; ++i)
            #pragma unroll
            for (int j = 0; j < 8; ++j) acc[i][j] = 0.f;

        for (int kt = 0; kt < E / BK; ++kt) {
            __syncthreads();   // protect LDS reads of previous chunk
            {
                const int kk = (tid & 15) * 4;
                const int rr = tid >> 4;
                #pragma unroll
                for (int m = 0; m < 4; ++m) {
                    int row = m * 16 + rr;
                    float4 v = *(const float4*)(x + (size_t)(r0 + row) * E + kt * BK + kk);
                    *(float4*)&xs[row][kk] = v;
                }
                #pragma unroll
                for (int m = 0; m < 8; ++m) {
                    int row = m * 16 + rr;
                    float4 v = *(const float4*)(w + (size_t)(c0 + row) * E + kt * BK + kk);
                    *(float4*)&ws[row][kk] = v;
                }
            }
            __syncthreads();

            #pragma unroll
            for (int k4 = 0; k4 < BK / 4; ++k4) {
                float4 a[4], b[8];
                #pragma unroll
                for (int i = 0; i < 4; ++i) a[i] = *(const float4*)&xs[tr + 16 * i][k4 * 4];
                #pragma unroll
                for (int j = 0; j < 8; ++j) b[j] = *(const float4*)&ws[tc + 16 * j][k4 * 4];
                #pragma unroll
                for (int i = 0; i < 4; ++i)
                    #pragma unroll
                    for (int j = 0; j < 8; ++j) {
                        acc[i][j] += a[i].x * b[j].x;
                        acc[i][j] += a[i].y * b[j].y;
                        acc[i][j] += a[i].z * b[j].z;
                        acc[i][j] += a[i].w * b[j].w;
                    }
            }
        }

        // Epilogue for this Q tile: score = fl(fl(x2 - 2*dot) + w2), fp32 —
        // replicate the reference's rounding so exact-tie structure matches.
        #pragma unroll
        for (int i = 0; i < 4; ++i) {
            #pragma unroll
            for (int j = 0; j < 8; ++j) {
                int c = c0 + tc + 16 * j;   // ascending in j -> first-index tie-break via strict <
                float s = (x2r[i] - 2.0f * acc[i][j]) + w2[c];
                if (s < best[i]) { best[i] = s; bidx[i] = c; }
            }
        }
    }

    // Merge 16 per-thread partials per row; lexicographic (score, idx) matches
    // np.argmin's first-occurrence rule on exact ties.
    #pragma unroll
    for (int i = 0; i < 4; ++i) {
        redS[tr + 16 * i][tc] = best[i];
        redC[tr + 16 * i][tc] = bidx[i];
    }
    __syncthreads();
    if (tid < BM) {
        float bs = FLT_MAX; int bc = 0x7FFFFFFF;
        #pragma unroll
        for (int t = 0; t < 16; ++t) {
            float s = redS[tid][t]; int c = redC[tid][t];
            if (s < bs || (s == bs && c < bc)) { bs = s; bc = c; }
        }
        qidx[r0 + tid] = (float)bc;   // exact for bc < 2^24
        bestC[tid] = bc;
    }
    __syncthreads();

    // q_data gather: one 64-lane wave covers one full 256-float row (1 KB, coalesced).
    for (int it = 0; it < BM / 4; ++it) {
        int row = it * 4 + (tid >> 6);
        int c   = bestC[row];
        int kk  = (tid & 63) * 4;
        float4 v = *(const float4*)(w + (size_t)c * E + kk);
        *(float4*)(qdata + (size_t)(r0 + row) * E + kk) = v;
    }
}

extern "C" void kernel_launch(void* const* d_in, const int* in_sizes, int n_in,
                              void* d_out, int out_size, void* d_ws, size_t ws_size,
                              hipStream_t stream) {
    const float* x = (const float*)d_in[0];   // (N, 256), N = 16*2048 = 32768
    const float* w = (const float*)d_in[1];   // (4096, 256)
    const int N = in_sizes[0] / E;            // 32768

    float* qdata = (float*)d_out;                       // N*E floats
    float* qidx  = (float*)d_out + (size_t)N * E;       // N floats (indices as float)

    float* x2 = (float*)d_ws;        // N floats
    float* w2 = x2 + N;              // Qn floats

    row_sumsq_kernel<<<N,  64, 0, stream>>>(x, x2);
    row_sumsq_kernel<<<Qn, 64, 0, stream>>>(w, w2);
    vq_kernel<<<N / BM, TH, 0, stream>>>(x, w, x2, w2, qdata, qidx);
}

// Round 2
// 373.901 us; speedup vs baseline: 5.6196x; 5.6196x over previous
//
#include <hip/hip_runtime.h>
#include <cfloat>

// Problem constants: x (16,2048,256) fp32 -> N=32768 rows; weight (4096,256) fp32.
constexpr int E  = 256;    // quantizing_dim
constexpr int Qn = 4096;   // num_quantizing
constexpr int Kp = 768;    // split GEMM K = 3*E  (segments [xh|xh|xl] . [wh|wl|wh])
constexpr float WSCALE = 4096.0f;   // 2^12: keeps wl in fp16 normal range; exact pow2

typedef _Float16 half8  __attribute__((ext_vector_type(8)));
typedef _Float16 half4v __attribute__((ext_vector_type(4)));
typedef float    f32x16 __attribute__((ext_vector_type(16)));

#define GAS __attribute__((address_space(1)))
#define LAS __attribute__((address_space(3)))

// ---------------------------------------------------------------------------
// Split kernels: one 64-lane wave per row. Also compute row sum-of-squares
// (butterfly order — identical structure to the round-1 kernel that passed
// with absmax 0).
// ---------------------------------------------------------------------------
__global__ __launch_bounds__(256) void split_x_kernel(const float* __restrict__ x,
                                                      _Float16* __restrict__ A,
                                                      float* __restrict__ x2) {
    int row  = blockIdx.x * 4 + (threadIdx.x >> 6);
    int lane = threadIdx.x & 63;
    float4 v = *(const float4*)(x + (size_t)row * E + lane * 4);

    float s = v.x * v.x + v.y * v.y + v.z * v.z + v.w * v.w;
    #pragma unroll
    for (int off = 32; off; off >>= 1) s += __shfl_xor(s, off);
    if (lane == 0) x2[row] = s;

    half4v h = { (_Float16)v.x, (_Float16)v.y, (_Float16)v.z, (_Float16)v.w };
    half4v l = { (_Float16)(v.x - (float)h.x), (_Float16)(v.y - (float)h.y),
                 (_Float16)(v.z - (float)h.z), (_Float16)(v.w - (float)h.w) };
    _Float16* Ar = A + (size_t)row * Kp;
    *(half4v*)(Ar +       lane * 4) = h;
    *(half4v*)(Ar + E   + lane * 4) = h;
    *(half4v*)(Ar + 2*E + lane * 4) = l;
}

__global__ __launch_bounds__(256) void split_w_kernel(const float* __restrict__ w,
                                                      _Float16* __restrict__ B,
                                                      float* __restrict__ w2) {
    int row  = blockIdx.x * 4 + (threadIdx.x >> 6);
    int lane = threadIdx.x & 63;
    float4 v = *(const float4*)(w + (size_t)row * E + lane * 4);

    float s = v.x * v.x + v.y * v.y + v.z * v.z + v.w * v.w;  // UNSCALED w2
    #pragma unroll
    for (int off = 32; off; off >>= 1) s += __shfl_xor(s, off);
    if (lane == 0) w2[row] = s;

    float4 vs = { v.x * WSCALE, v.y * WSCALE, v.z * WSCALE, v.w * WSCALE }; // exact
    half4v h = { (_Float16)vs.x, (_Float16)vs.y, (_Float16)vs.z, (_Float16)vs.w };
    half4v l = { (_Float16)(vs.x - (float)h.x), (_Float16)(vs.y - (float)h.y),
                 (_Float16)(vs.z - (float)h.z), (_Float16)(vs.w - (float)h.w) };
    _Float16* Br = B + (size_t)row * Kp;
    *(half4v*)(Br +       lane * 4) = h;
    *(half4v*)(Br + E   + lane * 4) = l;   // pairs with xh (segment 1)
    *(half4v*)(Br + 2*E + lane * 4) = h;   // pairs with xl (segment 2)
}

// ---------------------------------------------------------------------------
// Main MFMA kernel: block = 128 x-rows x 128 codewords, grid (N/128, Qn/128).
// C = W·X^T via mfma_f32_32x32x16_f16; per-row running top-2 (approx dist),
// written per (row, colgroup) to the top2 workspace.
// ---------------------------------------------------------------------------
__device__ inline void merge_top2(float& B1, int& I1, float& B2, int& I2,
                                  float c1, int j1, float c2, int j2) {
    // both (B1,B2) and (c1,c2) are lex-sorted pairs
    if (c1 < B1 || (c1 == B1 && j1 < I1)) {
        if (B1 < c2 || (B1 == c2 && I1 < j2)) { B2 = B1; I2 = I1; }
        else                                  { B2 = c2; I2 = j2; }
        B1 = c1; I1 = j1;
    } else {
        if (c1 < B2 || (c1 == B2 && j1 < I2)) { B2 = c1; I2 = j1; }
    }
}

__global__ __launch_bounds__(256, 3) void vq_mfma_kernel(
    const _Float16* __restrict__ A,   // (N, 768)  x splits
    const _Float16* __restrict__ B,   // (Qn, 768) w splits (scaled)
    const float* __restrict__ x2, const float* __restrict__ w2,
    float4* __restrict__ top2)        // (N, Qn/128) records {b1,i1,b2,i2}
{
    __shared__ _Float16 ldsW[128 * 64];   // 16 KB, 16B-chunk XOR swizzled
    __shared__ _Float16 ldsX[128 * 64];   // 16 KB
    __shared__ float    w2s[128];
    __shared__ float4   mergeS[128 * 4];  // 8 KB

    const int tid  = threadIdx.x;
    const int w    = tid >> 6;
    const int lane = tid & 63;
    const int l31  = lane & 31;
    const int lh   = lane >> 5;          // k-half select
    const int rb   = blockIdx.x;         // row band (128 x-rows)
    const int cg   = blockIdx.y;         // col group (128 codewords)

    if (tid < 128) w2s[tid] = w2[cg * 128 + tid];

    const int wr = (w & 1) * 64;         // wave's x-row quadrant base
    const int wc = (w >> 1) * 64;        // wave's codeword quadrant base

    f32x16 acc[2][2];
    #pragma unroll
    for (int f = 0; f < 2; ++f)
        #pragma unroll
        for (int g = 0; g < 2; ++g)
            #pragma unroll
            for (int r = 0; r < 16; ++r) acc[f][g][r] = 0.0f;

    const _Float16* Ab = A + (size_t)rb * 128 * Kp;
    const _Float16* Bb = B + (size_t)cg * 128 * Kp;

    const int srow = lane >> 3;   // staging: row-in-8 group
    const int schk = lane & 7;    // staging: dest 16B chunk

    for (int kt = 0; kt < Kp / 64; ++kt) {
        __syncthreads();
        #pragma unroll
        for (int inst = 0; inst < 4; ++inst) {
            int drow = w * 32 + inst * 8 + srow;          // 0..127 (block-local)
            int gchk = schk ^ (drow & 7);                 // source chunk (swizzle)
            const _Float16* gW = Bb + (size_t)drow * Kp + kt * 64 + gchk * 8;
            const _Float16* gX = Ab + (size_t)drow * Kp + kt * 64 + gchk * 8;
            __builtin_amdgcn_global_load_lds((const GAS void*)gW,
                (LAS void*)(ldsW + w * 2048 + inst * 512), 16, 0, 0);
            __builtin_amdgcn_global_load_lds((const GAS void*)gX,
                (LAS void*)(ldsX + w * 2048 + inst * 512), 16, 0, 0);
        }
        __syncthreads();

        #pragma unroll
        for (int s = 0; s < 4; ++s) {
            const int kc = 2 * s + lh;
            half8 wf[2], xf[2];
            #pragma unroll
            for (int f = 0; f < 2; ++f) {
                int fr = wc + 32 * f + l31;
                wf[f] = *(const half8*)(ldsW + fr * 64 + ((kc ^ (fr & 7)) << 3));
                int xr = wr + 32 * f + l31;
                xf[f] = *(const half8*)(ldsX + xr * 64 + ((kc ^ (xr & 7)) << 3));
            }
            #pragma unroll
            for (int f = 0; f < 2; ++f)
                #pragma unroll
                for (int g = 0; g < 2; ++g)
                    acc[f][g] = __builtin_amdgcn_mfma_f32_32x32x16_f16(
                        wf[f], xf[g], acc[f][g], 0, 0, 0);
        }
    }

    // ---- epilogue: approx dist + per-lane top-2 (ascending q, strict <) ----
    const float invS = 1.0f / WSCALE;
    float x2g[2];
    #pragma unroll
    for (int g = 0; g < 2; ++g) x2g[g] = x2[rb * 128 + wr + 32 * g + l31];

    float b1[2], b2[2]; int i1[2], i2[2];
    #pragma unroll
    for (int g = 0; g < 2; ++g) { b1[g] = FLT_MAX; b2[g] = FLT_MAX; i1[g] = 0x7FFFFFFF; i2[g] = 0x7FFFFFFF; }

    #pragma unroll
    for (int f = 0; f < 2; ++f)
        #pragma unroll
        for (int r = 0; r < 16; ++r) {
            int m  = (r & 3) + 8 * (r >> 2) + 4 * lh;     // C-row mapping (32x32)
            int ql = wc + 32 * f + m;                     // block-local codeword
            float w2c = w2s[ql];
            int  qg = cg * 128 + ql;
            #pragma unroll
            for (int g = 0; g < 2; ++g) {
                float dot = acc[f][g][r] * invS;                  // exact pow2 scale
                float sd  = (x2g[g] - 2.0f * dot) + w2c;          // reference rounding
                if (sd < b1[g]) { b2[g] = b1[g]; i2[g] = i1[g]; b1[g] = sd; i1[g] = qg; }
                else if (sd < b2[g]) { b2[g] = sd; i2[g] = qg; }
            }
        }

    #pragma unroll
    for (int g = 0; g < 2; ++g) {
        int rrow = wr + 32 * g + l31;
        mergeS[rrow * 4 + ((w >> 1) * 2 + lh)] =
            make_float4(b1[g], __int_as_float(i1[g]), b2[g], __int_as_float(i2[g]));
    }
    __syncthreads();

    if (tid < 128) {
        float4 a0 = mergeS[tid * 4 + 0];
        float B1 = a0.x; int I1 = __float_as_int(a0.y);
        float B2 = a0.z; int I2 = __float_as_int(a0.w);
        #pragma unroll
        for (int sl = 1; sl < 4; ++sl) {
            float4 a = mergeS[tid * 4 + sl];
            merge_top2(B1, I1, B2, I2, a.x, __float_as_int(a.y), a.z, __float_as_int(a.w));
        }
        top2[(size_t)(rb * 128 + tid) * (Qn / 128) + cg] =
            make_float4(B1, __int_as_float(I1), B2, __int_as_float(I2));
    }
}

// ---------------------------------------------------------------------------
// Finalize: merge 32 col-group top-2s per row, exact fp32 rescore of the two
// survivors (reference formula + first-index tie-break), write outputs.
// ---------------------------------------------------------------------------
__global__ __launch_bounds__(256) void finalize_kernel(
    const float4* __restrict__ top2, const float* __restrict__ x,
    const float* __restrict__ w, const float* __restrict__ x2,
    const float* __restrict__ w2, float* __restrict__ qdata,
    float* __restrict__ qidx)
{
    int row  = blockIdx.x * 4 + (threadIdx.x >> 6);
    int lane = threadIdx.x & 63;

    float4 rec = top2[(size_t)row * (Qn / 128) + (lane >> 1)];
    float b0; int i0;
    if (lane & 1) { b0 = rec.z; i0 = __float_as_int(rec.w); }
    else          { b0 = rec.x; i0 = __float_as_int(rec.y); }

    float b = b0; int i = i0;
    #pragma unroll
    for (int off = 32; off; off >>= 1) {
        float ob = __shfl_xor(b, off); int oi = __shfl_xor(i, off);
        if (ob < b || (ob == b && oi < i)) { b = ob; i = oi; }
    }
    const int I1 = i;

    b = (i0 == I1) ? FLT_MAX : b0; i = (i0 == I1) ? 0x7FFFFFFF : i0;
    #pragma unroll
    for (int off = 32; off; off >>= 1) {
        float ob = __shfl_xor(b, off); int oi = __shfl_xor(i, off);
        if (ob < b || (ob == b && oi < i)) { b = ob; i = oi; }
    }
    const int I2 = i;

    // exact fp32 rescore (same formula family as the validated round-1 kernel)
    float4 xv  = *(const float4*)(x + (size_t)row * E + lane * 4);
    float4 w1v = *(const float4*)(w + (size_t)I1 * E + lane * 4);
    float4 w2v = *(const float4*)(w + (size_t)I2 * E + lane * 4);
    float d1 = xv.x * w1v.x + xv.y * w1v.y + xv.z * w1v.z + xv.w * w1v.w;
    float d2 = xv.x * w2v.x + xv.y * w2v.y + xv.z * w2v.z + xv.w * w2v.w;
    #pragma unroll
    for (int off = 32; off; off >>= 1) { d1 += __shfl_xor(d1, off); d2 += __shfl_xor(d2, off); }

    float X2 = x2[row];
    float s1 = (X2 - 2.0f * d1) + w2[I1];
    float s2 = (X2 - 2.0f * d2) + w2[I2];
    int win = (s2 < s1) ? I2 : ((s1 < s2) ? I1 : (I1 < I2 ? I1 : I2));

    if (lane == 0) qidx[row] = (float)win;
    *(float4*)(qdata + (size_t)row * E + lane * 4) =
        *(const float4*)(w + (size_t)win * E + lane * 4);
}

// ---------------------------------------------------------------------------
// Round-1 fp32 fallback (used only if ws_size is too small). Passed absmax 0.
// ---------------------------------------------------------------------------
constexpr int FBM = 64, FBN = 128, FBK = 64, FPAD = 4, FTH = 256;

__global__ __launch_bounds__(64) void row_sumsq_kernel(const float* __restrict__ src,
                                                       float* __restrict__ dst) {
    int row = blockIdx.x, lane = threadIdx.x;
    float4 v = ((const float4*)(src + (size_t)row * E))[lane];
    float s = v.x * v.x + v.y * v.y + v.z * v.z + v.w * v.w;
    #pragma unroll
    for (int off = 32; off > 0; off >>= 1) s += __shfl_down(s, off);
    if (lane == 0) dst[row] = s;
}

__global__ __launch_bounds__(FTH) void vq_fallback_kernel(
    const float* __restrict__ x, const float* __restrict__ w,
    const float* __restrict__ x2, const float* __restrict__ w2,
    float* __restrict__ qdata, float* __restrict__ qidx)
{
    __shared__ float xs[FBM][FBK + FPAD];
    __shared__ float ws[FBN][FBK + FPAD];
    __shared__ float redS[FBM][16];
    __shared__ int   redC[FBM][16];
    __shared__ int   bestC[FBM];

    const int tid = threadIdx.x, tr = tid >> 4, tc = tid & 15;
    const int r0 = blockIdx.x * FBM;
    float best[4]; int bidx[4];
    #pragma unroll
    for (int i = 0; i < 4; ++i) { best[i] = FLT_MAX; bidx[i] = 0x7FFFFFFF; }
    float x2r[4];
    #pragma unroll
    for (int i = 0; i < 4; ++i) x2r[i] = x2[r0 + tr + 16 * i];

    for (int qt = 0; qt < Qn / FBN; ++qt) {
        const int c0 = qt * FBN;
        float acc[4][8];
        #pragma unroll
        for (int i = 0; i < 4; ++i)
            #pragma unroll
            for (int j = 0; j < 8; ++j) acc[i][j] = 0.f;
        for (int kt = 0; kt < E / FBK; ++kt) {
            __syncthreads();
            const int kk = (tid & 15) * 4, rr = tid >> 4;
            #pragma unroll
            for (int m = 0; m < 4; ++m)
                *(float4*)&xs[m * 16 + rr][kk] =
                    *(const float4*)(x + (size_t)(r0 + m * 16 + rr) * E + kt * FBK + kk);
            #pragma unroll
            for (int m = 0; m < 8; ++m)
                *(float4*)&ws[m * 16 + rr][kk] =
                    *(const float4*)(w + (size_t)(c0 + m * 16 + rr) * E + kt * FBK + kk);
            __syncthreads();
            #pragma unroll
            for (int k4 = 0; k4 < FBK / 4; ++k4) {
                float4 a[4], bb[8];
                #pragma unroll
                for (int i = 0; i < 4; ++i) a[i] = *(const float4*)&xs[tr + 16 * i][k4 * 4];
                #pragma unroll
                for (int j = 0; j < 8; ++j) bb[j] = *(const float4*)&ws[tc + 16 * j][k4 * 4];
                #pragma unroll
                for (int i = 0; i < 4; ++i)
                    #pragma unroll
                    for (int j = 0; j < 8; ++j) {
                        acc[i][j] += a[i].x * bb[j].x; acc[i][j] += a[i].y * bb[j].y;
                        acc[i][j] += a[i].z * bb[j].z; acc[i][j] += a[i].w * bb[j].w;
                    }
            }
        }
        #pragma unroll
        for (int i = 0; i < 4; ++i)
            #pragma unroll
            for (int j = 0; j < 8; ++j) {
                int c = c0 + tc + 16 * j;
                float s = (x2r[i] - 2.0f * acc[i][j]) + w2[c];
                if (s < best[i]) { best[i] = s; bidx[i] = c; }
            }
    }
    #pragma unroll
    for (int i = 0; i < 4; ++i) { redS[tr + 16 * i][tc] = best[i]; redC[tr + 16 * i][tc] = bidx[i]; }
    __syncthreads();
    if (tid < FBM) {
        float bs = FLT_MAX; int bc = 0x7FFFFFFF;
        #pragma unroll
        for (int t = 0; t < 16; ++t) {
            float s = redS[tid][t]; int c = redC[tid][t];
            if (s < bs || (s == bs && c < bc)) { bs = s; bc = c; }
        }
        qidx[r0 + tid] = (float)bc; bestC[tid] = bc;
    }
    __syncthreads();
    for (int it = 0; it < FBM / 4; ++it) {
        int row = it * 4 + (tid >> 6), c = bestC[row], kk = (tid & 63) * 4;
        *(float4*)(qdata + (size_t)(r0 + row) * E + kk) = *(const float4*)(w + (size_t)c * E + kk);
    }
}

// ---------------------------------------------------------------------------
extern "C" void kernel_launch(void* const* d_in, const int* in_sizes, int n_in,
                              void* d_out, int out_size, void* d_ws, size_t ws_size,
                              hipStream_t stream) {
    const float* x = (const float*)d_in[0];
    const float* w = (const float*)d_in[1];
    const int N = in_sizes[0] / E;                      // 32768

    float* qdata = (float*)d_out;
    float* qidx  = (float*)d_out + (size_t)N * E;

    // workspace carve (256B aligned)
    size_t off = 0;
    auto carve = [&](size_t bytes) { size_t p = off; off += (bytes + 255) & ~(size_t)255; return p; };
    size_t oA  = carve((size_t)N * Kp * sizeof(_Float16));     // 48 MB
    size_t oB  = carve((size_t)Qn * Kp * sizeof(_Float16));    // 6 MB
    size_t ox2 = carve((size_t)N * sizeof(float));
    size_t ow2 = carve((size_t)Qn * sizeof(float));
    size_t oT  = carve((size_t)N * (Qn / 128) * sizeof(float4)); // 16 MB

    if (ws_size >= off && (N % 128) == 0) {
        char* ws = (char*)d_ws;
        _Float16* A  = (_Float16*)(ws + oA);
        _Float16* B  = (_Float16*)(ws + oB);
        float* x2    = (float*)(ws + ox2);
        float* w2    = (float*)(ws + ow2);
        float4* top2 = (float4*)(ws + oT);

        split_x_kernel<<<N / 4, 256, 0, stream>>>(x, A, x2);
        split_w_kernel<<<Qn / 4, 256, 0, stream>>>(w, B, w2);
        vq_mfma_kernel<<<dim3(N / 128, Qn / 128), 256, 0, stream>>>(A, B, x2, w2, top2);
        finalize_kernel<<<N / 4, 256, 0, stream>>>(top2, x, w, x2, w2, qdata, qidx);
    } else {
        float* x2 = (float*)d_ws;
        float* w2 = x2 + N;
        row_sumsq_kernel<<<N, 64, 0, stream>>>(x, x2);
        row_sumsq_kernel<<<Qn, 64, 0, stream>>>(w, w2);
        vq_fallback_kernel<<<N / FBM, FTH, 0, stream>>>(x, w, x2, w2, qdata, qidx);
    }
}

// Round 3
// 363.705 us; speedup vs baseline: 5.7771x; 1.0280x over previous
//
#include <hip/hip_runtime.h>
#include <cfloat>

// Problem constants: x (16,2048,256) fp32 -> N=32768 rows; weight (4096,256) fp32.
constexpr int E  = 256;    // quantizing_dim
constexpr int Qn = 4096;   // num_quantizing
constexpr int Kp = 768;    // split GEMM K = 3*E  (segments [xh|xh|xl] . [wh|wl|wh])
constexpr float WSCALE = 4096.0f;   // 2^12: keeps wl in fp16 normal range; exact pow2

typedef _Float16 half8  __attribute__((ext_vector_type(8)));
typedef _Float16 half4v __attribute__((ext_vector_type(4)));
typedef float    f32x16 __attribute__((ext_vector_type(16)));

#define GAS __attribute__((address_space(1)))
#define LAS __attribute__((address_space(3)))

// ---------------------------------------------------------------------------
// Fused prep: one 64-lane wave per row for both x and w.
// Computes row sum-of-squares and the fp16 2-term split (3 GEMM segments).
// ---------------------------------------------------------------------------
__global__ __launch_bounds__(256) void prep_kernel(
    const float* __restrict__ x, const float* __restrict__ w,
    _Float16* __restrict__ A, _Float16* __restrict__ B,
    float* __restrict__ x2, float* __restrict__ w2, int nxblocks)
{
    int blk  = blockIdx.x;
    int sub  = threadIdx.x >> 6;
    int lane = threadIdx.x & 63;
    bool isX = blk < nxblocks;
    int row  = (isX ? blk : blk - nxblocks) * 4 + sub;

    const float* src = isX ? x : w;
    float4 v = *(const float4*)(src + (size_t)row * E + lane * 4);

    float s = v.x * v.x + v.y * v.y + v.z * v.z + v.w * v.w;   // UNSCALED sumsq
    #pragma unroll
    for (int off = 32; off; off >>= 1) s += __shfl_xor(s, off);
    if (lane == 0) (isX ? x2 : w2)[row] = s;

    float sc = isX ? 1.0f : WSCALE;                            // exact pow2 scale
    float4 vs = { v.x * sc, v.y * sc, v.z * sc, v.w * sc };
    half4v h = { (_Float16)vs.x, (_Float16)vs.y, (_Float16)vs.z, (_Float16)vs.w };
    half4v l = { (_Float16)(vs.x - (float)h.x), (_Float16)(vs.y - (float)h.y),
                 (_Float16)(vs.z - (float)h.z), (_Float16)(vs.w - (float)h.w) };
    _Float16* dst = (isX ? A : B) + (size_t)row * Kp;
    if (isX) {
        *(half4v*)(dst +       lane * 4) = h;   // xh
        *(half4v*)(dst + E   + lane * 4) = h;   // xh (pairs with wl)
        *(half4v*)(dst + 2*E + lane * 4) = l;   // xl (pairs with wh)
    } else {
        *(half4v*)(dst +       lane * 4) = h;   // wh
        *(half4v*)(dst + E   + lane * 4) = l;   // wl
        *(half4v*)(dst + 2*E + lane * 4) = h;   // wh
    }
}

// ---------------------------------------------------------------------------
// Main MFMA kernel: block = 128 x-rows x 128 codewords, grid (N/128, Qn/128).
// Ranking key = w2 - 2*dot (row-constant x2 dropped; finer grid than the
// reference's — near-tie discrepancies are rescued by top-2 + exact rescore).
// mergeS overlaid on staging LDS (union) -> 32.5 KB -> 4 blocks/CU.
// ---------------------------------------------------------------------------
__device__ inline void merge_top2(float& B1, int& I1, float& B2, int& I2,
                                  float c1, int j1, float c2, int j2) {
    if (c1 < B1 || (c1 == B1 && j1 < I1)) {
        if (B1 < c2 || (B1 == c2 && I1 < j2)) { B2 = B1; I2 = I1; }
        else                                  { B2 = c2; I2 = j2; }
        B1 = c1; I1 = j1;
    } else {
        if (c1 < B2 || (c1 == B2 && j1 < I2)) { B2 = c1; I2 = j1; }
    }
}

union SmemU {
    struct { _Float16 W[128 * 64]; _Float16 X[128 * 64]; } st;  // 32 KB staging
    float4 mergeS[128 * 4];                                      // 8 KB (post-loop)
};

__global__ __launch_bounds__(256, 4) void vq_mfma_kernel(
    const _Float16* __restrict__ A,   // (N, 768)  x splits
    const _Float16* __restrict__ B,   // (Qn, 768) w splits (scaled)
    const float* __restrict__ w2,
    float4* __restrict__ top2)        // (N, Qn/128) records {b1,i1,b2,i2}
{
    __shared__ SmemU sm;
    __shared__ float w2s[128];

    const int tid  = threadIdx.x;
    const int w    = tid >> 6;
    const int lane = tid & 63;
    const int l31  = lane & 31;
    const int lh   = lane >> 5;          // k-half select
    const int rb   = blockIdx.x;         // row band (128 x-rows)
    const int cg   = blockIdx.y;         // col group (128 codewords)

    if (tid < 128) w2s[tid] = w2[cg * 128 + tid];

    const int wr = (w & 1) * 64;         // wave's x-row quadrant base
    const int wc = (w >> 1) * 64;        // wave's codeword quadrant base

    f32x16 acc[2][2];
    #pragma unroll
    for (int f = 0; f < 2; ++f)
        #pragma unroll
        for (int g = 0; g < 2; ++g)
            #pragma unroll
            for (int r = 0; r < 16; ++r) acc[f][g][r] = 0.0f;

    const _Float16* Ab = A + (size_t)rb * 128 * Kp;
    const _Float16* Bb = B + (size_t)cg * 128 * Kp;

    const int srow = lane >> 3;   // staging: row-in-8 group
    const int schk = lane & 7;    // staging: dest 16B chunk

    for (int kt = 0; kt < Kp / 64; ++kt) {
        __syncthreads();
        #pragma unroll
        for (int inst = 0; inst < 4; ++inst) {
            int drow = w * 32 + inst * 8 + srow;          // 0..127 (block-local)
            int gchk = schk ^ (drow & 7);                 // source chunk (swizzle)
            const _Float16* gW = Bb + (size_t)drow * Kp + kt * 64 + gchk * 8;
            const _Float16* gX = Ab + (size_t)drow * Kp + kt * 64 + gchk * 8;
            __builtin_amdgcn_global_load_lds((const GAS void*)gW,
                (LAS void*)(sm.st.W + w * 2048 + inst * 512), 16, 0, 0);
            __builtin_amdgcn_global_load_lds((const GAS void*)gX,
                (LAS void*)(sm.st.X + w * 2048 + inst * 512), 16, 0, 0);
        }
        __syncthreads();

        #pragma unroll
        for (int s = 0; s < 4; ++s) {
            const int kc = 2 * s + lh;
            half8 wf[2], xf[2];
            #pragma unroll
            for (int f = 0; f < 2; ++f) {
                int fr = wc + 32 * f + l31;
                wf[f] = *(const half8*)(sm.st.W + fr * 64 + ((kc ^ (fr & 7)) << 3));
                int xr = wr + 32 * f + l31;
                xf[f] = *(const half8*)(sm.st.X + xr * 64 + ((kc ^ (xr & 7)) << 3));
            }
            #pragma unroll
            for (int f = 0; f < 2; ++f)
                #pragma unroll
                for (int g = 0; g < 2; ++g)
                    acc[f][g] = __builtin_amdgcn_mfma_f32_32x32x16_f16(
                        wf[f], xf[g], acc[f][g], 0, 0, 0);
        }
    }

    // ---- epilogue: key = w2 - 2*dot (scale folded); per-lane top-2 ----
    constexpr float KNEG = -2.0f / WSCALE;   // exact: -2^-11
    float b1[2], b2[2]; int i1[2], i2[2];
    #pragma unroll
    for (int g = 0; g < 2; ++g) { b1[g] = FLT_MAX; b2[g] = FLT_MAX; i1[g] = 0x7FFFFFFF; i2[g] = 0x7FFFFFFF; }

    #pragma unroll
    for (int f = 0; f < 2; ++f)
        #pragma unroll
        for (int r = 0; r < 16; ++r) {
            int m  = (r & 3) + 8 * (r >> 2) + 4 * lh;     // C-row mapping (32x32)
            int ql = wc + 32 * f + m;                     // block-local codeword
            float w2c = w2s[ql];
            int  qg = cg * 128 + ql;
            #pragma unroll
            for (int g = 0; g < 2; ++g) {
                float sd = fmaf(acc[f][g][r], KNEG, w2c);
                if (sd < b1[g]) { b2[g] = b1[g]; i2[g] = i1[g]; b1[g] = sd; i1[g] = qg; }
                else if (sd < b2[g]) { b2[g] = sd; i2[g] = qg; }
            }
        }

    __syncthreads();   // staging LDS reads done -> safe to overlay mergeS

    #pragma unroll
    for (int g = 0; g < 2; ++g) {
        int rrow = wr + 32 * g + l31;
        sm.mergeS[rrow * 4 + ((w >> 1) * 2 + lh)] =
            make_float4(b1[g], __int_as_float(i1[g]), b2[g], __int_as_float(i2[g]));
    }
    __syncthreads();

    if (tid < 128) {
        float4 a0 = sm.mergeS[tid * 4 + 0];
        float B1 = a0.x; int I1 = __float_as_int(a0.y);
        float B2 = a0.z; int I2 = __float_as_int(a0.w);
        #pragma unroll
        for (int sl = 1; sl < 4; ++sl) {
            float4 a = sm.mergeS[tid * 4 + sl];
            merge_top2(B1, I1, B2, I2, a.x, __float_as_int(a.y), a.z, __float_as_int(a.w));
        }
        top2[(size_t)(rb * 128 + tid) * (Qn / 128) + cg] =
            make_float4(B1, __int_as_float(I1), B2, __int_as_float(I2));
    }
}

// ---------------------------------------------------------------------------
// Finalize: merge 32 col-group top-2s per row, exact fp32 rescore of the two
// survivors (reference formula + first-index tie-break), write outputs.
// Numerics byte-identical to the round-2 validated version.
// ---------------------------------------------------------------------------
__global__ __launch_bounds__(256) void finalize_kernel(
    const float4* __restrict__ top2, const float* __restrict__ x,
    const float* __restrict__ w, const float* __restrict__ x2,
    const float* __restrict__ w2, float* __restrict__ qdata,
    float* __restrict__ qidx)
{
    int row  = blockIdx.x * 4 + (threadIdx.x >> 6);
    int lane = threadIdx.x & 63;

    float4 rec = top2[(size_t)row * (Qn / 128) + (lane >> 1)];
    float b0; int i0;
    if (lane & 1) { b0 = rec.z; i0 = __float_as_int(rec.w); }
    else          { b0 = rec.x; i0 = __float_as_int(rec.y); }

    float b = b0; int i = i0;
    #pragma unroll
    for (int off = 32; off; off >>= 1) {
        float ob = __shfl_xor(b, off); int oi = __shfl_xor(i, off);
        if (ob < b || (ob == b && oi < i)) { b = ob; i = oi; }
    }
    const int I1 = i;

    b = (i0 == I1) ? FLT_MAX : b0; i = (i0 == I1) ? 0x7FFFFFFF : i0;
    #pragma unroll
    for (int off = 32; off; off >>= 1) {
        float ob = __shfl_xor(b, off); int oi = __shfl_xor(i, off);
        if (ob < b || (ob == b && oi < i)) { b = ob; i = oi; }
    }
    const int I2 = i;

    // exact fp32 rescore (formula validated with absmax 0 in rounds 1-2)
    float4 xv  = *(const float4*)(x + (size_t)row * E + lane * 4);
    float4 w1v = *(const float4*)(w + (size_t)I1 * E + lane * 4);
    float4 w2v = *(const float4*)(w + (size_t)I2 * E + lane * 4);
    float d1 = xv.x * w1v.x + xv.y * w1v.y + xv.z * w1v.z + xv.w * w1v.w;
    float d2 = xv.x * w2v.x + xv.y * w2v.y + xv.z * w2v.z + xv.w * w2v.w;
    #pragma unroll
    for (int off = 32; off; off >>= 1) { d1 += __shfl_xor(d1, off); d2 += __shfl_xor(d2, off); }

    float X2 = x2[row];
    float s1 = (X2 - 2.0f * d1) + w2[I1];
    float s2 = (X2 - 2.0f * d2) + w2[I2];
    int win = (s2 < s1) ? I2 : ((s1 < s2) ? I1 : (I1 < I2 ? I1 : I2));

    if (lane == 0) qidx[row] = (float)win;
    *(float4*)(qdata + (size_t)row * E + lane * 4) =
        *(const float4*)(w + (size_t)win * E + lane * 4);
}

// ---------------------------------------------------------------------------
// Round-1 fp32 fallback (used only if ws_size is too small). Passed absmax 0.
// ---------------------------------------------------------------------------
constexpr int FBM = 64, FBN = 128, FBK = 64, FPAD = 4, FTH = 256;

__global__ __launch_bounds__(64) void row_sumsq_kernel(const float* __restrict__ src,
                                                       float* __restrict__ dst) {
    int row = blockIdx.x, lane = threadIdx.x;
    float4 v = ((const float4*)(src + (size_t)row * E))[lane];
    float s = v.x * v.x + v.y * v.y + v.z * v.z + v.w * v.w;
    #pragma unroll
    for (int off = 32; off > 0; off >>= 1) s += __shfl_down(s, off);
    if (lane == 0) dst[row] = s;
}

__global__ __launch_bounds__(FTH) void vq_fallback_kernel(
    const float* __restrict__ x, const float* __restrict__ w,
    const float* __restrict__ x2, const float* __restrict__ w2,
    float* __restrict__ qdata, float* __restrict__ qidx)
{
    __shared__ float xs[FBM][FBK + FPAD];
    __shared__ float ws[FBN][FBK + FPAD];
    __shared__ float redS[FBM][16];
    __shared__ int   redC[FBM][16];
    __shared__ int   bestC[FBM];

    const int tid = threadIdx.x, tr = tid >> 4, tc = tid & 15;
    const int r0 = blockIdx.x * FBM;
    float best[4]; int bidx[4];
    #pragma unroll
    for (int i = 0; i < 4; ++i) { best[i] = FLT_MAX; bidx[i] = 0x7FFFFFFF; }
    float x2r[4];
    #pragma unroll
    for (int i = 0; i < 4; ++i) x2r[i] = x2[r0 + tr + 16 * i];

    for (int qt = 0; qt < Qn / FBN; ++qt) {
        const int c0 = qt * FBN;
        float acc[4][8];
        #pragma unroll
        for (int i = 0; i < 4; ++i)
            #pragma unroll
            for (int j = 0; j < 8; ++j) acc[i][j] = 0.f;
        for (int kt = 0; kt < E / FBK; ++kt) {
            __syncthreads();
            const int kk = (tid & 15) * 4, rr = tid >> 4;
            #pragma unroll
            for (int m = 0; m < 4; ++m)
                *(float4*)&xs[m * 16 + rr][kk] =
                    *(const float4*)(x + (size_t)(r0 + m * 16 + rr) * E + kt * FBK + kk);
            #pragma unroll
            for (int m = 0; m < 8; ++m)
                *(float4*)&ws[m * 16 + rr][kk] =
                    *(const float4*)(w + (size_t)(c0 + m * 16 + rr) * E + kt * FBK + kk);
            __syncthreads();
            #pragma unroll
            for (int k4 = 0; k4 < FBK / 4; ++k4) {
                float4 a[4], bb[8];
                #pragma unroll
                for (int i = 0; i < 4; ++i) a[i] = *(const float4*)&xs[tr + 16 * i][k4 * 4];
                #pragma unroll
                for (int j = 0; j < 8; ++j) bb[j] = *(const float4*)&ws[tc + 16 * j][k4 * 4];
                #pragma unroll
                for (int i = 0; i < 4; ++i)
                    #pragma unroll
                    for (int j = 0; j < 8; ++j) {
                        acc[i][j] += a[i].x * bb[j].x; acc[i][j] += a[i].y * bb[j].y;
                        acc[i][j] += a[i].z * bb[j].z; acc[i][j] += a[i].w * bb[j].w;
                    }
            }
        }
        #pragma unroll
        for (int i = 0; i < 4; ++i)
            #pragma unroll
            for (int j = 0; j < 8; ++j) {
                int c = c0 + tc + 16 * j;
                float s = (x2r[i] - 2.0f * acc[i][j]) + w2[c];
                if (s < best[i]) { best[i] = s; bidx[i] = c; }
            }
    }
    #pragma unroll
    for (int i = 0; i < 4; ++i) { redS[tr + 16 * i][tc] = best[i]; redC[tr + 16 * i][tc] = bidx[i]; }
    __syncthreads();
    if (tid < FBM) {
        float bs = FLT_MAX; int bc = 0x7FFFFFFF;
        #pragma unroll
        for (int t = 0; t < 16; ++t) {
            float s = redS[tid][t]; int c = redC[tid][t];
            if (s < bs || (s == bs && c < bc)) { bs = s; bc = c; }
        }
        qidx[r0 + tid] = (float)bc; bestC[tid] = bc;
    }
    __syncthreads();
    for (int it = 0; it < FBM / 4; ++it) {
        int row = it * 4 + (tid >> 6), c = bestC[row], kk = (tid & 63) * 4;
        *(float4*)(qdata + (size_t)(r0 + row) * E + kk) = *(const float4*)(w + (size_t)c * E + kk);
    }
}

// ---------------------------------------------------------------------------
extern "C" void kernel_launch(void* const* d_in, const int* in_sizes, int n_in,
                              void* d_out, int out_size, void* d_ws, size_t ws_size,
                              hipStream_t stream) {
    const float* x = (const float*)d_in[0];
    const float* w = (const float*)d_in[1];
    const int N = in_sizes[0] / E;                      // 32768

    float* qdata = (float*)d_out;
    float* qidx  = (float*)d_out + (size_t)N * E;

    // workspace carve (256B aligned)
    size_t off = 0;
    auto carve = [&](size_t bytes) { size_t p = off; off += (bytes + 255) & ~(size_t)255; return p; };
    size_t oA  = carve((size_t)N * Kp * sizeof(_Float16));       // 48 MB
    size_t oB  = carve((size_t)Qn * Kp * sizeof(_Float16));      // 6 MB
    size_t ox2 = carve((size_t)N * sizeof(float));
    size_t ow2 = carve((size_t)Qn * sizeof(float));
    size_t oT  = carve((size_t)N * (Qn / 128) * sizeof(float4)); // 16 MB

    if (ws_size >= off && (N % 128) == 0) {
        char* ws = (char*)d_ws;
        _Float16* A  = (_Float16*)(ws + oA);
        _Float16* B  = (_Float16*)(ws + oB);
        float* x2    = (float*)(ws + ox2);
        float* w2    = (float*)(ws + ow2);
        float4* top2 = (float4*)(ws + oT);

        prep_kernel<<<N / 4 + Qn / 4, 256, 0, stream>>>(x, w, A, B, x2, w2, N / 4);
        vq_mfma_kernel<<<dim3(N / 128, Qn / 128), 256, 0, stream>>>(A, B, w2, top2);
        finalize_kernel<<<N / 4, 256, 0, stream>>>(top2, x, w, x2, w2, qdata, qidx);
    } else {
        float* x2 = (float*)d_ws;
        float* w2 = x2 + N;
        row_sumsq_kernel<<<N, 64, 0, stream>>>(x, x2);
        row_sumsq_kernel<<<Qn, 64, 0, stream>>>(w, w2);
        vq_fallback_kernel<<<N / FBM, FTH, 0, stream>>>(x, w, x2, w2, qdata, qidx);
    }
}